// Round 1
// baseline (144274.634 us; speedup 1.0000x reference)
//
#include <hip/hip_runtime.h>
#include <math.h>

// Problem constants (Elman RNN)
#define TT 4096
#define HH 2048
#define OO 512

// ---------------------------------------------------------------------------
// Phase 1 & 3: fp32 NT GEMM  C[m,n] = sum_k A[m,k]*B[n,k] + bias[n]
// 128x128 tile, 256 threads, 8x8 per thread, BK=8.
// ---------------------------------------------------------------------------
__global__ __launch_bounds__(256) void gemm_nt_bias(
    const float* __restrict__ A, const float* __restrict__ B,
    const float* __restrict__ bias, float* __restrict__ C,
    int M, int N, int K)
{
    __shared__ float As[8][128];
    __shared__ float Bs[8][128];

    const int tid = threadIdx.x;
    const int bm = blockIdx.x * 128;
    const int bn = blockIdx.y * 128;

    // staging load mapping: 256 threads, each one float4 of A and of B
    const int lrow = tid >> 1;          // 0..127
    const int lk   = (tid & 1) * 4;     // 0 or 4

    // compute mapping: 16x16 threads, each 8x8 split as (4+4)x(4+4)
    const int ty = tid >> 4;            // 0..15
    const int tx = tid & 15;            // 0..15

    float acc[8][8];
#pragma unroll
    for (int i = 0; i < 8; i++)
#pragma unroll
        for (int j = 0; j < 8; j++) acc[i][j] = 0.f;

    for (int k0 = 0; k0 < K; k0 += 8) {
        float4 av = *(const float4*)&A[(size_t)(bm + lrow) * K + k0 + lk];
        float4 bv = *(const float4*)&B[(size_t)(bn + lrow) * K + k0 + lk];
        __syncthreads();   // previous compute done before overwriting LDS
        As[lk + 0][lrow] = av.x; As[lk + 1][lrow] = av.y;
        As[lk + 2][lrow] = av.z; As[lk + 3][lrow] = av.w;
        Bs[lk + 0][lrow] = bv.x; Bs[lk + 1][lrow] = bv.y;
        Bs[lk + 2][lrow] = bv.z; Bs[lk + 3][lrow] = bv.w;
        __syncthreads();
#pragma unroll
        for (int kk = 0; kk < 8; kk++) {
            float a[8], b[8];
            *(float4*)&a[0] = *(const float4*)&As[kk][ty * 4];
            *(float4*)&a[4] = *(const float4*)&As[kk][64 + ty * 4];
            *(float4*)&b[0] = *(const float4*)&Bs[kk][tx * 4];
            *(float4*)&b[4] = *(const float4*)&Bs[kk][64 + tx * 4];
#pragma unroll
            for (int i = 0; i < 8; i++)
#pragma unroll
                for (int j = 0; j < 8; j++)
                    acc[i][j] += a[i] * b[j];
        }
    }

    // epilogue: add bias, store
#pragma unroll
    for (int g = 0; g < 2; g++) {
        const int n = bn + g * 64 + tx * 4;
        float4 bv = *(const float4*)&bias[n];
#pragma unroll
        for (int i = 0; i < 8; i++) {
            const int m = bm + ((i < 4) ? (ty * 4 + i) : (64 + ty * 4 + (i - 4)));
            float4 cv;
            cv.x = acc[i][g * 4 + 0] + bv.x;
            cv.y = acc[i][g * 4 + 1] + bv.y;
            cv.z = acc[i][g * 4 + 2] + bv.z;
            cv.w = acc[i][g * 4 + 3] + bv.w;
            *(float4*)&C[(size_t)m * N + n] = cv;
        }
    }
}

// ---------------------------------------------------------------------------
// Phase 2: persistent scan kernel.
// 256 blocks x 1024 threads, 1 block/CU. W_hh held in registers:
//   block b owns rows [8b, 8b+8); row r <- waves {2r, 2r+1};
//   thread (wave w, lane l): half = w&1, covers k = j*128 + half*64 + l, j=0..15.
// Per step: agent-scope h loads -> 16 FMA -> wave shuffle-reduce ->
// LDS pair combine -> tanh -> agent store -> release flag -> parallel flag poll.
// ---------------------------------------------------------------------------
__global__ __launch_bounds__(1024) void rnn_scan(
    const float* __restrict__ xp,    // (T,H) input projection incl. b_ih
    const float* __restrict__ Whh,   // (H,H)
    const float* __restrict__ bhh,   // (H)
    const float* __restrict__ h0,    // (H)
    float* __restrict__ outs,        // (T,H) hidden states out
    int* __restrict__ flags)         // 256 flags, stride 16 ints (64B)
{
    const int b    = blockIdx.x;     // 0..255
    const int tid  = threadIdx.x;    // 0..1023
    const int wave = tid >> 6;       // 0..15
    const int lane = tid & 63;
    const int row_local = wave >> 1; // 0..7
    const int half = wave & 1;
    const int row  = b * 8 + row_local;
    const int kbase = half * 64 + lane;   // 0..127

    // preload weights into registers (one-time, coalesced per j)
    float w[16];
#pragma unroll
    for (int j = 0; j < 16; j++)
        w[j] = Whh[(size_t)row * HH + j * 128 + kbase];

    const float bias = (tid < 8) ? bhh[b * 8 + tid] : 0.f;

    __shared__ float wsum[16];

    const float* hprev = h0;

    for (int t = 0; t < TT; ++t) {
        // issue xp load early (independent of h)
        float xpv = 0.f;
        if (tid < 8) xpv = xp[(size_t)t * HH + b * 8 + tid];

        // matvec partial: h loads are agent-scope (bypass stale L1/L2)
        float p = 0.f;
#pragma unroll
        for (int j = 0; j < 16; j++) {
            float hv = __hip_atomic_load(&hprev[j * 128 + kbase],
                                         __ATOMIC_RELAXED, __HIP_MEMORY_SCOPE_AGENT);
            p += w[j] * hv;
        }
        // in-wave reduce (64 lanes)
#pragma unroll
        for (int off = 32; off > 0; off >>= 1)
            p += __shfl_xor(p, off, 64);
        if (lane == 0) wsum[wave] = p;
        __syncthreads();

        if (tid < 8) {
            float s = wsum[2 * tid] + wsum[2 * tid + 1];
            float hv = tanhf(xpv + bias + s);
            __hip_atomic_store(&outs[(size_t)t * HH + b * 8 + tid], hv,
                               __ATOMIC_RELAXED, __HIP_MEMORY_SCOPE_AGENT);
        }
        if (tid == 0) {
            // release: prior agent stores of this wave visible before flag
            __hip_atomic_store(&flags[b * 16], t + 1,
                               __ATOMIC_RELEASE, __HIP_MEMORY_SCOPE_AGENT);
        }

        // distributed barrier: thread i polls block i's flag (no atomic contention)
        if (tid < 256) {
            while (__hip_atomic_load(&flags[tid * 16],
                                     __ATOMIC_RELAXED, __HIP_MEMORY_SCOPE_AGENT) < t + 1) {}
        }
        __syncthreads();
        __builtin_amdgcn_fence(__ATOMIC_ACQUIRE, "agent");

        hprev = outs + (size_t)t * HH;
    }
}

// ---------------------------------------------------------------------------
extern "C" void kernel_launch(void* const* d_in, const int* in_sizes, int n_in,
                              void* d_out, int out_size, void* d_ws, size_t ws_size,
                              hipStream_t stream)
{
    const float* x     = (const float*)d_in[0];  // (T,1,H)
    const float* W_ih  = (const float*)d_in[1];  // (H,H)
    const float* W_hh  = (const float*)d_in[2];  // (H,H)
    const float* b_ih  = (const float*)d_in[3];  // (H)
    const float* b_hh  = (const float*)d_in[4];  // (H)
    const float* W_lin = (const float*)d_in[5];  // (O,H)
    const float* b_lin = (const float*)d_in[6];  // (O)
    const float* h0    = (const float*)d_in[7];  // (1,1,H)
    float* out = (float*)d_out;                  // (T,1,O)

    char* ws = (char*)d_ws;
    float* xp   = (float*)ws;                        // 32 MB
    float* outs = (float*)(ws + (size_t)TT * HH * 4);        // 32 MB
    int*   flags = (int*)(ws + 2 * (size_t)TT * HH * 4);     // 16 KB

    // barrier flags must start at 0 (ws arrives poisoned)
    hipMemsetAsync(flags, 0, 256 * 16 * sizeof(int), stream);

    // Phase 1: xp = x @ W_ih^T + b_ih
    gemm_nt_bias<<<dim3(TT / 128, HH / 128), 256, 0, stream>>>(
        x, W_ih, b_ih, xp, TT, HH, HH);

    // Phase 2: sequential scan (persistent, one block per CU)
    rnn_scan<<<256, 1024, 0, stream>>>(xp, W_hh, b_hh, h0, outs, flags);

    // Phase 3: out = outs @ W_lin^T + b_lin
    gemm_nt_bias<<<dim3(TT / 128, OO / 128), 256, 0, stream>>>(
        outs, W_lin, b_lin, out, TT, OO, HH);
}

// Round 2
// 80341.150 us; speedup vs baseline: 1.7958x; 1.7958x over previous
//
#include <hip/hip_runtime.h>
#include <math.h>

// Problem constants (Elman RNN)
#define TT 4096
#define HH 2048
#define OO 512

#define NB  64    // scan blocks (fan-in of the all-to-all)
#define RPB 32    // rows per block = HH/NB

// ---------------------------------------------------------------------------
// Phase 1 & 3: fp32 NT GEMM  C[m,n] = sum_k A[m,k]*B[n,k] + bias[n]
// 128x128 tile, 256 threads, 8x8 per thread, BK=8. (unchanged this round)
// ---------------------------------------------------------------------------
__global__ __launch_bounds__(256) void gemm_nt_bias(
    const float* __restrict__ A, const float* __restrict__ B,
    const float* __restrict__ bias, float* __restrict__ C,
    int M, int N, int K)
{
    __shared__ float As[8][128];
    __shared__ float Bs[8][128];

    const int tid = threadIdx.x;
    const int bm = blockIdx.x * 128;
    const int bn = blockIdx.y * 128;

    const int lrow = tid >> 1;
    const int lk   = (tid & 1) * 4;

    const int ty = tid >> 4;
    const int tx = tid & 15;

    float acc[8][8];
#pragma unroll
    for (int i = 0; i < 8; i++)
#pragma unroll
        for (int j = 0; j < 8; j++) acc[i][j] = 0.f;

    for (int k0 = 0; k0 < K; k0 += 8) {
        float4 av = *(const float4*)&A[(size_t)(bm + lrow) * K + k0 + lk];
        float4 bv = *(const float4*)&B[(size_t)(bn + lrow) * K + k0 + lk];
        __syncthreads();
        As[lk + 0][lrow] = av.x; As[lk + 1][lrow] = av.y;
        As[lk + 2][lrow] = av.z; As[lk + 3][lrow] = av.w;
        Bs[lk + 0][lrow] = bv.x; Bs[lk + 1][lrow] = bv.y;
        Bs[lk + 2][lrow] = bv.z; Bs[lk + 3][lrow] = bv.w;
        __syncthreads();
#pragma unroll
        for (int kk = 0; kk < 8; kk++) {
            float a[8], b[8];
            *(float4*)&a[0] = *(const float4*)&As[kk][ty * 4];
            *(float4*)&a[4] = *(const float4*)&As[kk][64 + ty * 4];
            *(float4*)&b[0] = *(const float4*)&Bs[kk][tx * 4];
            *(float4*)&b[4] = *(const float4*)&Bs[kk][64 + tx * 4];
#pragma unroll
            for (int i = 0; i < 8; i++)
#pragma unroll
                for (int j = 0; j < 8; j++)
                    acc[i][j] += a[i] * b[j];
        }
    }

#pragma unroll
    for (int g = 0; g < 2; g++) {
        const int n = bn + g * 64 + tx * 4;
        float4 bv = *(const float4*)&bias[n];
#pragma unroll
        for (int i = 0; i < 8; i++) {
            const int m = bm + ((i < 4) ? (ty * 4 + i) : (64 + ty * 4 + (i - 4)));
            float4 cv;
            cv.x = acc[i][g * 4 + 0] + bv.x;
            cv.y = acc[i][g * 4 + 1] + bv.y;
            cv.z = acc[i][g * 4 + 2] + bv.z;
            cv.w = acc[i][g * 4 + 3] + bv.w;
            *(float4*)&C[(size_t)m * N + n] = cv;
        }
    }
}

// ---------------------------------------------------------------------------
// Phase 2: persistent scan, 64 blocks x 1024 threads.
// Block b owns rows [32b, 32b+32). Wave w: rows 2w (lanes 0-31), 2w+1 (32-63).
// Thread (wave w, lane l): sub=l>>5, c=l&31, covers k = c + 32*j, j=0..63.
// W_hh in registers (64 floats/thread, ~100 VGPR total, 16 waves/CU OK).
//
// Per step: xp load (early) -> 64 agent-scope h loads (bypass L1/L2, read L3
// directly -> NO acquire fence needed) -> 5-shuffle reduce -> tanh ->
// agent store -> __syncthreads (drains vmcnt: stores visible at L3) ->
// release flag -> wave 0 polls all 64 flags in ONE load -> barrier.
// ---------------------------------------------------------------------------
__global__ __launch_bounds__(1024, 4) void rnn_scan(
    const float* __restrict__ xp,    // (T,H) input projection incl. b_ih
    const float* __restrict__ Whh,   // (H,H)
    const float* __restrict__ bhh,   // (H)
    const float* __restrict__ h0,    // (H)
    float* __restrict__ outs,        // (T,H) hidden states out
    int* __restrict__ flags)         // NB flags, stride 16 ints (64B)
{
    const int b    = blockIdx.x;     // 0..63
    const int tid  = threadIdx.x;    // 0..1023
    const int wave = tid >> 6;       // 0..15
    const int lane = tid & 63;
    const int sub  = lane >> 5;      // 0/1
    const int c    = lane & 31;      // column lane within row
    const int row  = b * RPB + wave * 2 + sub;

    // preload weights into registers (coalesced: 32 consecutive floats/half-wave)
    float w[64];
#pragma unroll
    for (int j = 0; j < 64; ++j)
        w[j] = Whh[(size_t)row * HH + c + 32 * j];

    const float bias = bhh[row];

    const float* hprev = h0;

    for (int t = 0; t < TT; ++t) {
        // xp load issued early, overlaps h-load latency (independent of h)
        float xpv = (c == 0) ? xp[(size_t)t * HH + row] : 0.f;

        // matvec partial: agent-scope loads read L3 directly (no stale cache)
        float p = 0.f;
#pragma unroll
        for (int j = 0; j < 64; ++j) {
            float hv = __hip_atomic_load(&hprev[c + 32 * j],
                                         __ATOMIC_RELAXED, __HIP_MEMORY_SCOPE_AGENT);
            p += w[j] * hv;
        }
        // reduce across the 32 column lanes (stays within each half-wave)
#pragma unroll
        for (int off = 16; off > 0; off >>= 1)
            p += __shfl_xor(p, off, 64);

        if (c == 0) {
            float hv = tanhf(xpv + bias + p);
            __hip_atomic_store(&outs[(size_t)t * HH + row], hv,
                               __ATOMIC_RELAXED, __HIP_MEMORY_SCOPE_AGENT);
        }

        // barrier drains each wave's vmcnt -> all 32 row-stores are at L3
        __syncthreads();

        if (tid == 0)
            __hip_atomic_store(&flags[b * 16], t + 1,
                               __ATOMIC_RELEASE, __HIP_MEMORY_SCOPE_AGENT);

        // wave 0: all 64 flags polled in a single load instruction
        if (wave == 0) {
            int v;
            do {
                v = __hip_atomic_load(&flags[lane * 16],
                                      __ATOMIC_RELAXED, __HIP_MEMORY_SCOPE_AGENT);
            } while (__all(v > t) == 0);
        }
        __syncthreads();
        asm volatile("" ::: "memory");  // compiler-only ordering; NO hw fence

        hprev = outs + (size_t)t * HH;
    }
}

// ---------------------------------------------------------------------------
extern "C" void kernel_launch(void* const* d_in, const int* in_sizes, int n_in,
                              void* d_out, int out_size, void* d_ws, size_t ws_size,
                              hipStream_t stream)
{
    const float* x     = (const float*)d_in[0];  // (T,1,H)
    const float* W_ih  = (const float*)d_in[1];  // (H,H)
    const float* W_hh  = (const float*)d_in[2];  // (H,H)
    const float* b_ih  = (const float*)d_in[3];  // (H)
    const float* b_hh  = (const float*)d_in[4];  // (H)
    const float* W_lin = (const float*)d_in[5];  // (O,H)
    const float* b_lin = (const float*)d_in[6];  // (O)
    const float* h0    = (const float*)d_in[7];  // (1,1,H)
    float* out = (float*)d_out;                  // (T,1,O)

    char* ws = (char*)d_ws;
    float* xp    = (float*)ws;                               // 32 MB
    float* outs  = (float*)(ws + (size_t)TT * HH * 4);       // 32 MB
    int*   flags = (int*)(ws + 2 * (size_t)TT * HH * 4);     // 4 KB

    // barrier flags must start at 0 (ws arrives poisoned)
    hipMemsetAsync(flags, 0, NB * 16 * sizeof(int), stream);

    // Phase 1: xp = x @ W_ih^T + b_ih
    gemm_nt_bias<<<dim3(TT / 128, HH / 128), 256, 0, stream>>>(
        x, W_ih, b_ih, xp, TT, HH, HH);

    // Phase 2: sequential scan (persistent, 64 co-resident blocks)
    rnn_scan<<<NB, 1024, 0, stream>>>(xp, W_hh, b_hh, h0, outs, flags);

    // Phase 3: out = outs @ W_lin^T + b_lin
    gemm_nt_bias<<<dim3(TT / 128, OO / 128), 256, 0, stream>>>(
        outs, W_lin, b_lin, out, TT, OO, HH);
}

// Round 3
// 13082.889 us; speedup vs baseline: 11.0277x; 6.1409x over previous
//
#include <hip/hip_runtime.h>
#include <math.h>

// Problem constants (Elman RNN)
#define TT 4096
#define HH 2048
#define OO 512

#define NB  64    // scan blocks
#define RPB 32    // rows per block = HH/NB

// ---------------------------------------------------------------------------
// Phase 1 & 3: fp32 NT GEMM  C[m,n] = sum_k A[m,k]*B[n,k] + bias[n]
// 128x128 tile, 256 threads, 8x8 per thread, BK=8. (unchanged this round)
// ---------------------------------------------------------------------------
__global__ __launch_bounds__(256) void gemm_nt_bias(
    const float* __restrict__ A, const float* __restrict__ B,
    const float* __restrict__ bias, float* __restrict__ C,
    int M, int N, int K)
{
    __shared__ float As[8][128];
    __shared__ float Bs[8][128];

    const int tid = threadIdx.x;
    const int bm = blockIdx.x * 128;
    const int bn = blockIdx.y * 128;

    const int lrow = tid >> 1;
    const int lk   = (tid & 1) * 4;

    const int ty = tid >> 4;
    const int tx = tid & 15;

    float acc[8][8];
#pragma unroll
    for (int i = 0; i < 8; i++)
#pragma unroll
        for (int j = 0; j < 8; j++) acc[i][j] = 0.f;

    for (int k0 = 0; k0 < K; k0 += 8) {
        float4 av = *(const float4*)&A[(size_t)(bm + lrow) * K + k0 + lk];
        float4 bv = *(const float4*)&B[(size_t)(bn + lrow) * K + k0 + lk];
        __syncthreads();
        As[lk + 0][lrow] = av.x; As[lk + 1][lrow] = av.y;
        As[lk + 2][lrow] = av.z; As[lk + 3][lrow] = av.w;
        Bs[lk + 0][lrow] = bv.x; Bs[lk + 1][lrow] = bv.y;
        Bs[lk + 2][lrow] = bv.z; Bs[lk + 3][lrow] = bv.w;
        __syncthreads();
#pragma unroll
        for (int kk = 0; kk < 8; kk++) {
            float a[8], b[8];
            *(float4*)&a[0] = *(const float4*)&As[kk][ty * 4];
            *(float4*)&a[4] = *(const float4*)&As[kk][64 + ty * 4];
            *(float4*)&b[0] = *(const float4*)&Bs[kk][tx * 4];
            *(float4*)&b[4] = *(const float4*)&Bs[kk][64 + tx * 4];
#pragma unroll
            for (int i = 0; i < 8; i++)
#pragma unroll
                for (int j = 0; j < 8; j++)
                    acc[i][j] += a[i] * b[j];
        }
    }

#pragma unroll
    for (int g = 0; g < 2; g++) {
        const int n = bn + g * 64 + tx * 4;
        float4 bv = *(const float4*)&bias[n];
#pragma unroll
        for (int i = 0; i < 8; i++) {
            const int m = bm + ((i < 4) ? (ty * 4 + i) : (64 + ty * 4 + (i - 4)));
            float4 cv;
            cv.x = acc[i][g * 4 + 0] + bv.x;
            cv.y = acc[i][g * 4 + 1] + bv.y;
            cv.z = acc[i][g * 4 + 2] + bv.z;
            cv.w = acc[i][g * 4 + 3] + bv.w;
            *(float4*)&C[(size_t)m * N + n] = cv;
        }
    }
}

// ---------------------------------------------------------------------------
// Phase 2: persistent scan, 64 blocks x 1024 threads, block owns 32 rows.
//
// KEY CHANGE vs R2: h crosses the fabric ONCE per block per step (2 agent
// loads/thread -> LDS), instead of once per half-wave-row (32x duplication,
// 1024 L2-bypass vmem instr/CU/step -> was the latency bottleneck).
//
// Matvec layout: lane&31 = local row, wave*128 + (lane>>5)*64 = k-chunk.
// All 32 lanes of a half-wave read the SAME float4 of hs -> LDS broadcast
// (2 distinct addrs per ds_read_b128 = free). 64 weights/thread in VGPRs.
// Partials -> LDS[32][32], wave 0 reduces, tanh, agent store, release flag,
// single-instruction 64-flag poll.
// ---------------------------------------------------------------------------
__global__ __launch_bounds__(1024, 4) void rnn_scan(
    const float* __restrict__ xp,    // (T,H) input projection incl. b_ih
    const float* __restrict__ Whh,   // (H,H)
    const float* __restrict__ bhh,   // (H)
    const float* __restrict__ h0,    // (H)
    float* __restrict__ outs,        // (T,H) hidden states out
    int* __restrict__ flags)         // NB flags, stride 16 ints (64B)
{
    const int b    = blockIdx.x;     // 0..63
    const int tid  = threadIdx.x;    // 0..1023
    const int wave = tid >> 6;       // 0..15
    const int lane = tid & 63;
    const int sub  = lane >> 5;      // 0/1
    const int r    = lane & 31;      // local row 0..31
    const int row  = b * RPB + r;    // global row this thread accumulates
    const int k0   = wave * 128 + sub * 64;  // k-chunk start
    const int grp  = wave * 2 + sub;         // 0..31 partial group

    // weights: w[j] = Whh[row][k0+j]  (one-time, L1-cached streaming)
    float w[64];
#pragma unroll
    for (int j = 0; j < 64; ++j)
        w[j] = Whh[(size_t)row * HH + k0 + j];

    const float bias = (tid < 32) ? bhh[b * RPB + tid] : 0.f;

    __shared__ float hs[HH];             // staged h (8 KB)
    __shared__ float partial[32][32];    // [grp][row]

    const float* hprev = h0;

    for (int t = 0; t < TT; ++t) {
        // xp load: independent of h, issue first to hide under staging
        float xpv = (tid < 32) ? xp[(size_t)t * HH + b * RPB + tid] : 0.f;

        // stage h -> LDS: one coherent fetch per block (64 line reqs/CU)
        float hv0 = __hip_atomic_load(&hprev[tid],
                                      __ATOMIC_RELAXED, __HIP_MEMORY_SCOPE_AGENT);
        float hv1 = __hip_atomic_load(&hprev[tid + 1024],
                                      __ATOMIC_RELAXED, __HIP_MEMORY_SCOPE_AGENT);
        hs[tid] = hv0;
        hs[tid + 1024] = hv1;
        __syncthreads();   // staging complete

        // matvec partial: 16 broadcast ds_read_b128 + 64 FMA
        const float* hk = &hs[k0];
        float p = 0.f;
#pragma unroll
        for (int jj = 0; jj < 16; ++jj) {
            float4 h4 = *(const float4*)&hk[jj * 4];
            p += w[jj * 4 + 0] * h4.x + w[jj * 4 + 1] * h4.y
               + w[jj * 4 + 2] * h4.z + w[jj * 4 + 3] * h4.w;
        }
        partial[grp][r] = p;
        __syncthreads();   // partials visible

        if (tid < 32) {
            float s = 0.f;
#pragma unroll
            for (int g = 0; g < 32; ++g) s += partial[g][tid];
            float hv = tanhf(xpv + bias + s);
            __hip_atomic_store(&outs[(size_t)t * HH + b * RPB + tid], hv,
                               __ATOMIC_RELAXED, __HIP_MEMORY_SCOPE_AGENT);
        }
        if (tid == 0) {
            // release: waits vmcnt(0) -> wave 0's outs store is at coherence pt
            __hip_atomic_store(&flags[b * 16], t + 1,
                               __ATOMIC_RELEASE, __HIP_MEMORY_SCOPE_AGENT);
        }

        // wave 0: all 64 flags in one load instruction
        if (wave == 0) {
            int v;
            do {
                v = __hip_atomic_load(&flags[lane * 16],
                                      __ATOMIC_RELAXED, __HIP_MEMORY_SCOPE_AGENT);
            } while (__all(v > t) == 0);
        }
        __syncthreads();   // step boundary
        asm volatile("" ::: "memory");

        hprev = outs + (size_t)t * HH;
    }
}

// ---------------------------------------------------------------------------
extern "C" void kernel_launch(void* const* d_in, const int* in_sizes, int n_in,
                              void* d_out, int out_size, void* d_ws, size_t ws_size,
                              hipStream_t stream)
{
    const float* x     = (const float*)d_in[0];  // (T,1,H)
    const float* W_ih  = (const float*)d_in[1];  // (H,H)
    const float* W_hh  = (const float*)d_in[2];  // (H,H)
    const float* b_ih  = (const float*)d_in[3];  // (H)
    const float* b_hh  = (const float*)d_in[4];  // (H)
    const float* W_lin = (const float*)d_in[5];  // (O,H)
    const float* b_lin = (const float*)d_in[6];  // (O)
    const float* h0    = (const float*)d_in[7];  // (1,1,H)
    float* out = (float*)d_out;                  // (T,1,O)

    char* ws = (char*)d_ws;
    float* xp    = (float*)ws;                               // 32 MB
    float* outs  = (float*)(ws + (size_t)TT * HH * 4);       // 32 MB
    int*   flags = (int*)(ws + 2 * (size_t)TT * HH * 4);     // 4 KB

    // barrier flags must start at 0 (ws arrives poisoned)
    hipMemsetAsync(flags, 0, NB * 16 * sizeof(int), stream);

    // Phase 1: xp = x @ W_ih^T + b_ih
    gemm_nt_bias<<<dim3(TT / 128, HH / 128), 256, 0, stream>>>(
        x, W_ih, b_ih, xp, TT, HH, HH);

    // Phase 2: sequential scan (persistent, 64 co-resident blocks)
    rnn_scan<<<NB, 1024, 0, stream>>>(xp, W_hh, b_hh, h0, outs, flags);

    // Phase 3: out = outs @ W_lin^T + b_lin
    gemm_nt_bias<<<dim3(TT / 128, OO / 128), 256, 0, stream>>>(
        outs, W_lin, b_lin, out, TT, OO, HH);
}

// Round 4
// 9617.332 us; speedup vs baseline: 15.0015x; 1.3603x over previous
//
#include <hip/hip_runtime.h>
#include <math.h>

// Problem constants (Elman RNN)
#define TT 4096
#define HH 2048
#define OO 512

#define NB  64    // scan blocks
#define RPB 32    // rows per block = HH/NB

// ---------------------------------------------------------------------------
// Phase 1 & 3: fp32 NT GEMM  C[m,n] = sum_k A[m,k]*B[n,k] + bias[n]
// 128x128 tile, 256 threads, 8x8 per thread, BK=8. (unchanged this round)
// ---------------------------------------------------------------------------
__global__ __launch_bounds__(256) void gemm_nt_bias(
    const float* __restrict__ A, const float* __restrict__ B,
    const float* __restrict__ bias, float* __restrict__ C,
    int M, int N, int K)
{
    __shared__ float As[8][128];
    __shared__ float Bs[8][128];

    const int tid = threadIdx.x;
    const int bm = blockIdx.x * 128;
    const int bn = blockIdx.y * 128;

    const int lrow = tid >> 1;
    const int lk   = (tid & 1) * 4;

    const int ty = tid >> 4;
    const int tx = tid & 15;

    float acc[8][8];
#pragma unroll
    for (int i = 0; i < 8; i++)
#pragma unroll
        for (int j = 0; j < 8; j++) acc[i][j] = 0.f;

    for (int k0 = 0; k0 < K; k0 += 8) {
        float4 av = *(const float4*)&A[(size_t)(bm + lrow) * K + k0 + lk];
        float4 bv = *(const float4*)&B[(size_t)(bn + lrow) * K + k0 + lk];
        __syncthreads();
        As[lk + 0][lrow] = av.x; As[lk + 1][lrow] = av.y;
        As[lk + 2][lrow] = av.z; As[lk + 3][lrow] = av.w;
        Bs[lk + 0][lrow] = bv.x; Bs[lk + 1][lrow] = bv.y;
        Bs[lk + 2][lrow] = bv.z; Bs[lk + 3][lrow] = bv.w;
        __syncthreads();
#pragma unroll
        for (int kk = 0; kk < 8; kk++) {
            float a[8], b[8];
            *(float4*)&a[0] = *(const float4*)&As[kk][ty * 4];
            *(float4*)&a[4] = *(const float4*)&As[kk][64 + ty * 4];
            *(float4*)&b[0] = *(const float4*)&Bs[kk][tx * 4];
            *(float4*)&b[4] = *(const float4*)&Bs[kk][64 + tx * 4];
#pragma unroll
            for (int i = 0; i < 8; i++)
#pragma unroll
                for (int j = 0; j < 8; j++)
                    acc[i][j] += a[i] * b[j];
        }
    }

#pragma unroll
    for (int g = 0; g < 2; g++) {
        const int n = bn + g * 64 + tx * 4;
        float4 bv = *(const float4*)&bias[n];
#pragma unroll
        for (int i = 0; i < 8; i++) {
            const int m = bm + ((i < 4) ? (ty * 4 + i) : (64 + ty * 4 + (i - 4)));
            float4 cv;
            cv.x = acc[i][g * 4 + 0] + bv.x;
            cv.y = acc[i][g * 4 + 1] + bv.y;
            cv.z = acc[i][g * 4 + 2] + bv.z;
            cv.w = acc[i][g * 4 + 3] + bv.w;
            *(float4*)&C[(size_t)m * N + n] = cv;
        }
    }
}

// ---------------------------------------------------------------------------
// Phase 2: persistent scan, 64 blocks x 1024 threads, block owns 32 rows.
//
// R4 changes:
//  (a) FUSED data+flag mailbox: each h element is an 8B word
//      (tag<<32 | float_bits), stored with ONE relaxed agent-scope atomic.
//      Consumers poll the data itself (tag == t) -> one fabric round trip
//      instead of flag-RT + data-RT. Double-buffered by step parity
//      (safe: tag t+2 can only be written after all blocks consumed tag t).
//      t==0 reads h0 directly, so poisoned tags (0xAAAAAAAA) never match.
//  (b) Weights pinned in VGPRs via __hip_atomic_load(WORKGROUP) -- atomic
//      loads can't be rematerialized into the loop (R3's VGPR_Count=60
//      proved w[64] was being re-streamed from L1/L2 every step).
//  (c) 2 barriers/step instead of 3; plain (cached) stores to `outs`,
//      flushed by the kernel-end release before phase 3 runs.
// ---------------------------------------------------------------------------
__global__ __launch_bounds__(1024, 4) void rnn_scan(
    const float* __restrict__ xp,    // (T,H) input projection incl. b_ih
    const float* __restrict__ Whh,   // (H,H)
    const float* __restrict__ bhh,   // (H)
    const float* __restrict__ h0,    // (H)
    float* __restrict__ outs,        // (T,H) hidden states out
    unsigned long long* __restrict__ mbox)  // [2][HH] tagged-h mailbox
{
    const int b    = blockIdx.x;     // 0..63
    const int tid  = threadIdx.x;    // 0..1023
    const int wave = tid >> 6;       // 0..15
    const int lane = tid & 63;
    const int sub  = lane >> 5;      // 0/1
    const int r    = lane & 31;      // local row 0..31
    const int row  = b * RPB + r;    // global row this thread accumulates
    const int k0   = wave * 128 + sub * 64;  // k-chunk start
    const int grp  = wave * 2 + sub;         // 0..31 partial group

    // weights pinned in VGPRs: atomic loads cannot be sunk into the loop
    float w[64];
#pragma unroll
    for (int j = 0; j < 64; ++j)
        w[j] = __hip_atomic_load(&Whh[(size_t)row * HH + k0 + j],
                                 __ATOMIC_RELAXED, __HIP_MEMORY_SCOPE_WORKGROUP);

    const float bias = (tid < 32) ? bhh[b * RPB + tid] : 0.f;

    __shared__ float hs[HH];             // staged h (8 KB)
    __shared__ float partial[32][32];    // [grp][row]

    const int i0 = tid * 2, i1 = tid * 2 + 1;

    for (int t = 0; t < TT; ++t) {
        // xp load: independent of h, issues early, consumed late
        float xpv = (tid < 32) ? xp[(size_t)t * HH + b * RPB + tid] : 0.f;

        if (t == 0) {
            hs[i0] = h0[i0];
            hs[i1] = h0[i1];
        } else {
            const unsigned int want = (unsigned int)t;
            const unsigned long long* mb = mbox + (size_t)(t & 1) * HH;
            unsigned long long v0 = __hip_atomic_load(&mb[i0],
                __ATOMIC_RELAXED, __HIP_MEMORY_SCOPE_AGENT);
            unsigned long long v1 = __hip_atomic_load(&mb[i1],
                __ATOMIC_RELAXED, __HIP_MEMORY_SCOPE_AGENT);
            while ((unsigned int)(v0 >> 32) != want)
                v0 = __hip_atomic_load(&mb[i0],
                    __ATOMIC_RELAXED, __HIP_MEMORY_SCOPE_AGENT);
            while ((unsigned int)(v1 >> 32) != want)
                v1 = __hip_atomic_load(&mb[i1],
                    __ATOMIC_RELAXED, __HIP_MEMORY_SCOPE_AGENT);
            hs[i0] = __uint_as_float((unsigned int)v0);
            hs[i1] = __uint_as_float((unsigned int)v1);
        }
        __syncthreads();   // (A) staging complete

        // matvec partial: 16 broadcast ds_read_b128 + 64 FMA
        const float* hk = &hs[k0];
        float p = 0.f;
#pragma unroll
        for (int jj = 0; jj < 16; ++jj) {
            float4 h4 = *(const float4*)&hk[jj * 4];
            p += w[jj * 4 + 0] * h4.x + w[jj * 4 + 1] * h4.y
               + w[jj * 4 + 2] * h4.z + w[jj * 4 + 3] * h4.w;
        }
        partial[grp][r] = p;
        __syncthreads();   // (B) partials visible; hs reads done

        if (tid < 32) {
            float s = 0.f;
#pragma unroll
            for (int g = 0; g < 32; ++g) s += partial[g][tid];
            float hv = tanhf(xpv + bias + s);
            const int grow = b * RPB + tid;
            outs[(size_t)t * HH + grow] = hv;   // plain cached store
            unsigned long long pk =
                ((unsigned long long)(unsigned int)(t + 1) << 32) |
                (unsigned long long)__float_as_uint(hv);
            __hip_atomic_store(&mbox[(size_t)((t + 1) & 1) * HH + grow], pk,
                               __ATOMIC_RELAXED, __HIP_MEMORY_SCOPE_AGENT);
        }
        // no step-end barrier needed: next poll only touches mbox/hs-own-slots,
        // and partial[] is protected by barrier (A) of the next iteration.
    }
}

// ---------------------------------------------------------------------------
extern "C" void kernel_launch(void* const* d_in, const int* in_sizes, int n_in,
                              void* d_out, int out_size, void* d_ws, size_t ws_size,
                              hipStream_t stream)
{
    const float* x     = (const float*)d_in[0];  // (T,1,H)
    const float* W_ih  = (const float*)d_in[1];  // (H,H)
    const float* W_hh  = (const float*)d_in[2];  // (H,H)
    const float* b_ih  = (const float*)d_in[3];  // (H)
    const float* b_hh  = (const float*)d_in[4];  // (H)
    const float* W_lin = (const float*)d_in[5];  // (O,H)
    const float* b_lin = (const float*)d_in[6];  // (O)
    const float* h0    = (const float*)d_in[7];  // (1,1,H)
    float* out = (float*)d_out;                  // (T,1,O)

    char* ws = (char*)d_ws;
    float* xp    = (float*)ws;                                       // 32 MB
    float* outs  = (float*)(ws + (size_t)TT * HH * 4);               // 32 MB
    unsigned long long* mbox =
        (unsigned long long*)(ws + 2 * (size_t)TT * HH * 4);         // 32 KB

    // no mailbox init needed: t==0 reads h0 directly; poisoned tag
    // 0xAAAAAAAA never equals a wanted tag (t < 4096).

    // Phase 1: xp = x @ W_ih^T + b_ih
    gemm_nt_bias<<<dim3(TT / 128, HH / 128), 256, 0, stream>>>(
        x, W_ih, b_ih, xp, TT, HH, HH);

    // Phase 2: sequential scan (persistent, 64 co-resident blocks)
    rnn_scan<<<NB, 1024, 0, stream>>>(xp, W_hh, b_hh, h0, outs, mbox);

    // Phase 3: out = outs @ W_lin^T + b_lin
    gemm_nt_bias<<<dim3(TT / 128, OO / 128), 256, 0, stream>>>(
        outs, W_lin, b_lin, out, TT, OO, HH);
}